// Round 1
// baseline (160.692 us; speedup 1.0000x reference)
//
#include <hip/hip_runtime.h>

#define MAXLEN 20
#define DIM 1024
#define NB 16384

// One block per row b. 256 threads; thread i owns float4 slot i of the
// 1024-wide feature dim (1024/4 = 256 float4s).
// L = sum(mask[b]); weights w[t] = 0.5^(L-1-t) / (2*(1 - 2^-L)), all exact
// powers-of-two arithmetic except the final normalization multiply.
__global__ __launch_bounds__(256) void tdap_kernel(
    const float* __restrict__ x,     // [NB, MAXLEN, DIM]
    const int*   __restrict__ mask,  // [NB, MAXLEN]
    float*       __restrict__ out)   // [NB, DIM]
{
    const int b   = blockIdx.x;
    const int tid = threadIdx.x;  // 0..255

    // Valid length: sum of the mask row. Address is lane-uniform -> scalar loads.
    int L = 0;
#pragma unroll
    for (int t = 0; t < MAXLEN; ++t) L += mask[b * MAXLEN + t];

    // Normalization: sum_{k=0}^{L-1} 0.5^k = 2*(1 - 2^-L), exact in fp32 for L<=20.
    const float inv_norm = 1.0f / (2.0f * (1.0f - ldexpf(1.0f, -L)));
    // Weight at t=0 is 0.5^(L-1); doubles each step.
    float w = ldexpf(1.0f, -(L - 1)) * inv_norm;

    const float4* xp = reinterpret_cast<const float4*>(x + (size_t)b * MAXLEN * DIM) + tid;
    float4 acc = make_float4(0.f, 0.f, 0.f, 0.f);

    // L is block-uniform -> no divergence; only the first L tokens are read,
    // cutting HBM fetch to ~52% of the full tensor on average.
    for (int t = 0; t < L; ++t) {
        float4 v = xp[(size_t)t * (DIM / 4)];
        acc.x = fmaf(w, v.x, acc.x);
        acc.y = fmaf(w, v.y, acc.y);
        acc.z = fmaf(w, v.z, acc.z);
        acc.w = fmaf(w, v.w, acc.w);
        w *= 2.0f;
    }

    reinterpret_cast<float4*>(out + (size_t)b * DIM)[tid] = acc;
}

extern "C" void kernel_launch(void* const* d_in, const int* in_sizes, int n_in,
                              void* d_out, int out_size, void* d_ws, size_t ws_size,
                              hipStream_t stream) {
    const float* x    = (const float*)d_in[0];
    const int*   mask = (const int*)d_in[1];
    float*       out  = (float*)d_out;
    tdap_kernel<<<NB, 256, 0, stream>>>(x, mask, out);
}

// Round 2
// 158.381 us; speedup vs baseline: 1.0146x; 1.0146x over previous
//
#include <hip/hip_runtime.h>

#define MAXLEN 20
#define DIM 1024
#define NB 16384

// One block per row b. 256 threads; thread i owns float4 slot i of the
// 1024-wide feature dim. Weights are exact powers of two (alpha = 0.5):
// w[t] = 2^-(L-1-t) / (2*(1 - 2^-L)). 4-way token unroll with independent
// accumulators (weight ratios 1,2,4,8 folded in the epilogue) so each wave
// keeps 4 global_load_dwordx4 (4 KB) in flight instead of 1.
__global__ __launch_bounds__(256) void tdap_kernel(
    const float* __restrict__ x,     // [NB, MAXLEN, DIM]
    const int*   __restrict__ mask,  // [NB, MAXLEN]
    float*       __restrict__ out)   // [NB, DIM]
{
    const int b   = blockIdx.x;
    const int tid = threadIdx.x;  // 0..255

    // Valid length (lane-uniform -> compiler emits wide s_loads + scalar adds).
    int L = 0;
#pragma unroll
    for (int t = 0; t < MAXLEN; ++t) L += mask[b * MAXLEN + t];

    // norm = sum_{k=0}^{L-1} 0.5^k = 2*(1 - 2^-L), exact in fp32 for L<=20.
    const float inv_norm = 1.0f / (2.0f * (1.0f - ldexpf(1.0f, -L)));
    // Weight of token 0 (smallest): 0.5^(L-1) * inv_norm.
    float w = ldexpf(1.0f, -(L - 1)) * inv_norm;

    const float4* xp = reinterpret_cast<const float4*>(x + (size_t)b * MAXLEN * DIM) + tid;

    float4 a0 = make_float4(0.f, 0.f, 0.f, 0.f);
    float4 a1 = make_float4(0.f, 0.f, 0.f, 0.f);
    float4 a2 = make_float4(0.f, 0.f, 0.f, 0.f);
    float4 a3 = make_float4(0.f, 0.f, 0.f, 0.f);

    int t = 0;
    // Main: 4 tokens/iter. Token t+j carries weight w * 2^j; accumulate each
    // lane j into its own accumulator with multiplier w, fold the 2^j at the end.
    for (; t + 4 <= L; t += 4) {
        float4 v0 = xp[(size_t)(t + 0) * (DIM / 4)];
        float4 v1 = xp[(size_t)(t + 1) * (DIM / 4)];
        float4 v2 = xp[(size_t)(t + 2) * (DIM / 4)];
        float4 v3 = xp[(size_t)(t + 3) * (DIM / 4)];
        a0.x = fmaf(w, v0.x, a0.x); a0.y = fmaf(w, v0.y, a0.y);
        a0.z = fmaf(w, v0.z, a0.z); a0.w = fmaf(w, v0.w, a0.w);
        a1.x = fmaf(w, v1.x, a1.x); a1.y = fmaf(w, v1.y, a1.y);
        a1.z = fmaf(w, v1.z, a1.z); a1.w = fmaf(w, v1.w, a1.w);
        a2.x = fmaf(w, v2.x, a2.x); a2.y = fmaf(w, v2.y, a2.y);
        a2.z = fmaf(w, v2.z, a2.z); a2.w = fmaf(w, v2.w, a2.w);
        a3.x = fmaf(w, v3.x, a3.x); a3.y = fmaf(w, v3.y, a3.y);
        a3.z = fmaf(w, v3.z, a3.z); a3.w = fmaf(w, v3.w, a3.w);
        w *= 16.0f;  // exact: power-of-two scale
    }
    // Tail (0..3 tokens), exact weight per token, multiplier 1 -> a0.
    for (; t < L; ++t) {
        float4 v = xp[(size_t)t * (DIM / 4)];
        a0.x = fmaf(w, v.x, a0.x); a0.y = fmaf(w, v.y, a0.y);
        a0.z = fmaf(w, v.z, a0.z); a0.w = fmaf(w, v.w, a0.w);
        w *= 2.0f;
    }

    // acc = a0 + 2*a1 + 4*a2 + 8*a3 (exact power-of-two scales).
    float4 acc;
    acc.x = fmaf(8.f, a3.x, fmaf(4.f, a2.x, fmaf(2.f, a1.x, a0.x)));
    acc.y = fmaf(8.f, a3.y, fmaf(4.f, a2.y, fmaf(2.f, a1.y, a0.y)));
    acc.z = fmaf(8.f, a3.z, fmaf(4.f, a2.z, fmaf(2.f, a1.z, a0.z)));
    acc.w = fmaf(8.f, a3.w, fmaf(4.f, a2.w, fmaf(2.f, a1.w, a0.w)));

    reinterpret_cast<float4*>(out + (size_t)b * DIM)[tid] = acc;
}

extern "C" void kernel_launch(void* const* d_in, const int* in_sizes, int n_in,
                              void* d_out, int out_size, void* d_ws, size_t ws_size,
                              hipStream_t stream) {
    const float* x    = (const float*)d_in[0];
    const int*   mask = (const int*)d_in[1];
    float*       out  = (float*)d_out;
    tdap_kernel<<<NB, 256, 0, stream>>>(x, mask, out);
}